// Round 5
// baseline (708.120 us; speedup 1.0000x reference)
//
#include <hip/hip_runtime.h>

#define T_STEPS 100
#define BATCH   512
#define FIN     784
#define O1      100
#define O2      10
#define KC1     28      // K-chunk for k1 (784 = 28 * 28)

typedef __attribute__((ext_vector_type(4))) double f64x4;

// ---------------------------------------------------------------------------
// K0: f64-MFMA D-layout probe (validated rounds 3-4). Assumes only A-row =
// lane&15, B-col = lane&15. maps[l*8+r] = D-row, maps[l*8+4+r] = D-col.
// ---------------------------------------------------------------------------
__global__ __launch_bounds__(64) void k0_probe(int* __restrict__ maps) {
  const int l = threadIdx.x;
  const f64x4 z = {0.0, 0.0, 0.0, 0.0};
  f64x4 pr = __builtin_amdgcn_mfma_f64_16x16x4f64((double)(l & 15), 0.25, z, 0, 0, 0);
  f64x4 pc = __builtin_amdgcn_mfma_f64_16x16x4f64(0.25, (double)(l & 15), z, 0, 0, 0);
#pragma unroll
  for (int r = 0; r < 4; ++r) {
    int rm = (int)(pr[r] + 0.5); rm = rm < 0 ? 0 : (rm > 15 ? 15 : rm);
    int cm = (int)(pc[r] + 0.5); cm = cm < 0 ? 0 : (cm > 15 ? 15 : cm);
    maps[l * 8 + r]     = rm;
    maps[l * 8 + 4 + r] = cm;
  }
}

// ---------------------------------------------------------------------------
// K0b: W1 f32 -> f64 once (627 KB, stays L2/L3-hot for k1's A-frag reads).
// ---------------------------------------------------------------------------
__global__ __launch_bounds__(256) void k0b_w1d(const float* __restrict__ W1,
                                               double* __restrict__ W1d) {
  const int i = blockIdx.x * 256 + threadIdx.x;
  if (i < FIN * O1) W1d[i] = (double)W1[i];
}

// ---------------------------------------------------------------------------
// K1 v3: fused C-mean + f64 MFMA GEMM, pipelined.
//   I1T[t][o][b] = sum_f 0.5*(in[b,t,f,0]+in[b,t,f,1]) * W1[f,o]
// Block = (64 b-rows, one t), 4 waves, all 7 o-tiles {0,16,..,80,84} per wave
// (last overlaps -> bitwise-identical duplicate stores). Changes vs v2:
//  - W1 NOT staged in LDS: A-frags read from global W1d (f64, L2-hot; 7 loads
//    share one vaddr via imm offsets). Kills 2800 redundant LDS writes/chunk.
//  - Input tile double-buffered in LDS (AI[2][28][65], 29 KB); chunk c+1's
//    global loads issued BEFORE chunk c's MFMA phase (T14 async-stage split),
//    ds_write after compute, ONE barrier per chunk.
// Frag reads: 16-lane groups hit 128B contiguous; 4 k-rows at +520B -> all 32
// banks per group = inherent b64 4-phase minimum (conflict-free).
// ---------------------------------------------------------------------------
__global__ __launch_bounds__(256) void k1_mfma(const float* __restrict__ in,
                                               const double* __restrict__ W1d,
                                               const int* __restrict__ maps,
                                               double* __restrict__ I1T) {
  __shared__ double AI[2][KC1][65];   // [buf][f-in-chunk][b]
  const int tid = threadIdx.x;
  const int l   = tid & 63;
  const int w   = tid >> 6;
  const int r16 = l & 15;
  const int q16 = l >> 4;
  const int b0  = (int)blockIdx.x * 64;
  const int t   = (int)blockIdx.y;

  const int4 rm = *reinterpret_cast<const int4*>(maps + l * 8);
  const int4 cm = *reinterpret_cast<const int4*>(maps + l * 8 + 4);

  // staging slots: i = p*256+tid -> row = i/14, q = i%14 (14 float4 per row)
  bool act[4]; int rw[4], qq[4]; const float* bp[4];
#pragma unroll
  for (int p = 0; p < 4; ++p) {
    const int i = p * 256 + tid;
    act[p] = (i < 896);
    rw[p]  = i / 14;
    qq[p]  = i - rw[p] * 14;
    const int rsafe = act[p] ? rw[p] : 0;
    bp[p] = in + ((size_t)(b0 + rsafe) * T_STEPS + t) * (FIN * 2) + qq[p] * 4;
  }

  f64x4 acc[7];
#pragma unroll
  for (int n = 0; n < 7; ++n) acc[n] = (f64x4){0.0, 0.0, 0.0, 0.0};

  // prologue: stage chunk 0
  float4 st[4];
#pragma unroll
  for (int p = 0; p < 4; ++p)
    if (act[p]) st[p] = *reinterpret_cast<const float4*>(bp[p]);
#pragma unroll
  for (int p = 0; p < 4; ++p)
    if (act[p]) {
      AI[0][qq[p] * 2 + 0][rw[p]] = 0.5 * ((double)st[p].x + (double)st[p].y);
      AI[0][qq[p] * 2 + 1][rw[p]] = 0.5 * ((double)st[p].z + (double)st[p].w);
    }
  __syncthreads();

  for (int c = 0; c < FIN / KC1; ++c) {
    // issue next chunk's global loads early (land under the MFMA phase)
    if (c < FIN / KC1 - 1) {
#pragma unroll
      for (int p = 0; p < 4; ++p)
        if (act[p]) st[p] = *reinterpret_cast<const float4*>(bp[p] + (c + 1) * 56);
    }
    // compute chunk c: B-frags from LDS buf[c&1], A-frags from global W1d
    const double (*cur)[65] = (const double (*)[65])AI[c & 1];
    const double* Wb = W1d + (size_t)(c * KC1 + q16) * O1 + r16;
#pragma unroll
    for (int q = 0; q < KC1 / 4; ++q) {
      const double bv = cur[q * 4 + q16][w * 16 + r16];
      const double* wr = Wb + (size_t)q * 4 * O1;
      acc[0] = __builtin_amdgcn_mfma_f64_16x16x4f64(wr[0],  bv, acc[0], 0, 0, 0);
      acc[1] = __builtin_amdgcn_mfma_f64_16x16x4f64(wr[16], bv, acc[1], 0, 0, 0);
      acc[2] = __builtin_amdgcn_mfma_f64_16x16x4f64(wr[32], bv, acc[2], 0, 0, 0);
      acc[3] = __builtin_amdgcn_mfma_f64_16x16x4f64(wr[48], bv, acc[3], 0, 0, 0);
      acc[4] = __builtin_amdgcn_mfma_f64_16x16x4f64(wr[64], bv, acc[4], 0, 0, 0);
      acc[5] = __builtin_amdgcn_mfma_f64_16x16x4f64(wr[80], bv, acc[5], 0, 0, 0);
      acc[6] = __builtin_amdgcn_mfma_f64_16x16x4f64(wr[84], bv, acc[6], 0, 0, 0);
    }
    // write staged chunk c+1 into the other buffer (safe: last read of that
    // buffer was chunk c-1, protected by the previous barrier)
    if (c < FIN / KC1 - 1) {
#pragma unroll
      for (int p = 0; p < 4; ++p)
        if (act[p]) {
          AI[(c + 1) & 1][qq[p] * 2 + 0][rw[p]] = 0.5 * ((double)st[p].x + (double)st[p].y);
          AI[(c + 1) & 1][qq[p] * 2 + 1][rw[p]] = 0.5 * ((double)st[p].z + (double)st[p].w);
        }
    }
    __syncthreads();
  }

  double* base = I1T + (size_t)t * O1 * BATCH + (b0 + w * 16);
  const int otab[7] = {0, 16, 32, 48, 64, 80, 84};
#pragma unroll
  for (int n = 0; n < 7; ++n) {
    const int o0 = otab[n];
    base[(size_t)(o0 + rm.x) * BATCH + cm.x] = acc[n][0];
    base[(size_t)(o0 + rm.y) * BATCH + cm.y] = acc[n][1];
    base[(size_t)(o0 + rm.z) * BATCH + cm.z] = acc[n][2];
    base[(size_t)(o0 + rm.w) * BATCH + cm.w] = acc[n][3];
  }
}

// ---------------------------------------------------------------------------
// K2: BN stats per (t,o) row: mu, rstd. One wave per row.
// ---------------------------------------------------------------------------
__global__ __launch_bounds__(256) void k2_bnstats(const double* __restrict__ I1T,
                                                  double* __restrict__ mu,
                                                  double* __restrict__ rstd) {
  const int r    = blockIdx.x * 4 + (threadIdx.x >> 6);
  const int lane = threadIdx.x & 63;
  const double2* row2 = reinterpret_cast<const double2*>(I1T + (size_t)r * BATCH) + lane * 4;
  double v[8];
#pragma unroll
  for (int u = 0; u < 4; ++u) {
    double2 p = row2[u];
    v[2 * u] = p.x; v[2 * u + 1] = p.y;
  }
  double s = 0.0;
#pragma unroll
  for (int u = 0; u < 8; ++u) s += v[u];
#pragma unroll
  for (int m = 32; m >= 1; m >>= 1) s += __shfl_xor(s, m, 64);
  const double mean = s / 512.0;
  double q = 0.0;
#pragma unroll
  for (int u = 0; u < 8; ++u) { double d = v[u] - mean; q += d * d; }
#pragma unroll
  for (int m = 32; m >= 1; m >>= 1) q += __shfl_xor(q, m, 64);
  if (lane == 0) {
    mu[r]   = mean;
    rstd[r] = 1.0 / sqrt(q / 512.0 + 1e-5);
  }
}

// ---------------------------------------------------------------------------
// K3: layer-1 LIF scan. Block = o, thread = b.
// ---------------------------------------------------------------------------
__global__ __launch_bounds__(512) void k3_lif1(const double* __restrict__ I1T,
                                               const double* __restrict__ mu,
                                               const double* __restrict__ rstd,
                                               const float* __restrict__ scale,
                                               const float* __restrict__ bias,
                                               float* __restrict__ z1T) {
  const int o = blockIdx.x;
  const int b = threadIdx.x;
  const double sc = (double)scale[o], bs = (double)bias[o];
  double v = 0.0;
  for (int tc = 0; tc < T_STEPS; tc += 10) {
    double x[10], muv[10], rsv[10];
#pragma unroll
    for (int u = 0; u < 10; ++u) {
      const int t = tc + u;
      x[u]   = I1T[((size_t)t * O1 + o) * BATCH + b];
      muv[u] = mu[t * O1 + o];
      rsv[u] = rstd[t * O1 + o];
    }
#pragma unroll
    for (int u = 0; u < 10; ++u) {
      const double i = ((x[u] - muv[u]) * rsv[u]) * sc + bs;
      v = 0.95 * v + i;
      const bool z = (v > 1.0);
      z1T[((size_t)(tc + u) * O1 + o) * BATCH + b] = z ? 1.0f : 0.0f;
      if (z) v = 0.0;
    }
  }
}

// ---------------------------------------------------------------------------
// K4: I2[t][j][b] = sum_o z1T[t][o][b] * W2[o][j].
// ---------------------------------------------------------------------------
__global__ __launch_bounds__(512) void k4_proj2(const float* __restrict__ z1T,
                                                const float* __restrict__ W2,
                                                double* __restrict__ I2) {
  __shared__ double W2_lds[O1 * O2];
  const int t = blockIdx.x;
  const int b = threadIdx.x;
  for (int i = threadIdx.x; i < O1 * O2; i += 512) W2_lds[i] = (double)W2[i];
  __syncthreads();
  double acc[O2];
#pragma unroll
  for (int j = 0; j < O2; ++j) acc[j] = 0.0;
  for (int o = 0; o < O1; ++o) {
    const double z = (double)z1T[((size_t)t * O1 + o) * BATCH + b];
#pragma unroll
    for (int j = 0; j < O2; ++j) acc[j] += z * W2_lds[o * O2 + j];
  }
#pragma unroll
  for (int j = 0; j < O2; ++j)
    I2[((size_t)t * O2 + j) * BATCH + b] = acc[j];
}

// ---------------------------------------------------------------------------
// K5: layer-2 LIF scan + time-mean.
// ---------------------------------------------------------------------------
__global__ __launch_bounds__(512) void k5_lif2(const double* __restrict__ I2,
                                               float* __restrict__ out) {
  const int j = blockIdx.x;
  const int b = threadIdx.x;
  double v = 0.0;
  int cnt = 0;
  for (int tc = 0; tc < T_STEPS; tc += 10) {
    double x[10];
#pragma unroll
    for (int u = 0; u < 10; ++u)
      x[u] = I2[((size_t)(tc + u) * O2 + j) * BATCH + b];
#pragma unroll
    for (int u = 0; u < 10; ++u) {
      v = 0.95 * v + x[u];
      if (v > 1.0) { ++cnt; v = 0.0; }
    }
  }
  out[b * O2 + j] = (float)((double)cnt / 100.0);
}

// ---------------------------------------------------------------------------
extern "C" void kernel_launch(void* const* d_in, const int* in_sizes, int n_in,
                              void* d_out, int out_size, void* d_ws, size_t ws_size,
                              hipStream_t stream) {
  const float* in    = (const float*)d_in[0];
  const float* W1    = (const float*)d_in[2];
  const float* scale = (const float*)d_in[3];
  const float* bias  = (const float*)d_in[4];
  const float* W2    = (const float*)d_in[5];
  float* out = (float*)d_out;

  char* ws = (char*)d_ws;
  size_t off = 0;
  int*    maps = (int*)(ws + off);    off += 4096;
  double* W1d  = (double*)(ws + off); off += (size_t)FIN * O1 * sizeof(double);             // 627 KB
  double* I1T  = (double*)(ws + off); off += (size_t)T_STEPS * O1 * BATCH * sizeof(double);
  double* mu   = (double*)(ws + off); off += (size_t)T_STEPS * O1 * sizeof(double);
  double* rstd = (double*)(ws + off); off += (size_t)T_STEPS * O1 * sizeof(double);
  float*  z1T  = (float*)(ws + off);  off += (size_t)T_STEPS * O1 * BATCH * sizeof(float);
  double* I2   = (double*)(ws + off); off += (size_t)T_STEPS * O2 * BATCH * sizeof(double);

  k0_probe  <<<dim3(1), 64, 0, stream>>>(maps);
  k0b_w1d   <<<dim3((FIN * O1 + 255) / 256), 256, 0, stream>>>(W1, W1d);
  k1_mfma   <<<dim3(BATCH / 64, T_STEPS), 256, 0, stream>>>(in, W1d, maps, I1T);
  k2_bnstats<<<dim3(T_STEPS * O1 / 4), 256, 0, stream>>>(I1T, mu, rstd);
  k3_lif1   <<<dim3(O1), 512, 0, stream>>>(I1T, mu, rstd, scale, bias, z1T);
  k4_proj2  <<<dim3(T_STEPS), 512, 0, stream>>>(z1T, W2, I2);
  k5_lif2   <<<dim3(O2), 512, 0, stream>>>(I2, out);
}

// Round 6
// 431.191 us; speedup vs baseline: 1.6422x; 1.6422x over previous
//
#include <hip/hip_runtime.h>

#define T_STEPS 100
#define BATCH   512
#define FIN     784
#define O1      100
#define O2      10
#define KC1     28      // K-chunk (784 = 28 * 28)
#define NC1     (FIN / KC1)

typedef __attribute__((ext_vector_type(4))) double f64x4;

// ---------------------------------------------------------------------------
// K0: f64-MFMA D-layout probe (validated rounds 3-5). Assumes only A-row =
// lane&15, B-col = lane&15. maps[l*8+r] = D-row, maps[l*8+4+r] = D-col.
// ---------------------------------------------------------------------------
__global__ __launch_bounds__(64) void k0_probe(int* __restrict__ maps) {
  const int l = threadIdx.x;
  const f64x4 z = {0.0, 0.0, 0.0, 0.0};
  f64x4 pr = __builtin_amdgcn_mfma_f64_16x16x4f64((double)(l & 15), 0.25, z, 0, 0, 0);
  f64x4 pc = __builtin_amdgcn_mfma_f64_16x16x4f64(0.25, (double)(l & 15), z, 0, 0, 0);
#pragma unroll
  for (int r = 0; r < 4; ++r) {
    int rm = (int)(pr[r] + 0.5); rm = rm < 0 ? 0 : (rm > 15 ? 15 : rm);
    int cm = (int)(pc[r] + 0.5); cm = cm < 0 ? 0 : (cm > 15 ? 15 : cm);
    maps[l * 8 + r]     = rm;
    maps[l * 8 + 4 + r] = cm;
  }
}

// ---------------------------------------------------------------------------
// K1 v4: fused C-mean + f64 MFMA GEMM.
//   I1T[t][o][b] = sum_f 0.5*(in[b,t,f,0]+in[b,t,f,1]) * W1[f,o]
// Block = 512 thr = 8 waves, covers (64 b-rows, one t). Wave (wb,wo):
// wb=w&3 -> b-tile b0+16*wb; wo=w>>2 -> o-tiles {0,16,32,48} or {64,80,84}.
// (last tile overlaps at 84 -> duplicate stores bitwise identical).
// Both operands staged in LDS (W as f64, input C-meaned f64). Per chunk:
//   barrier; ds_write(c, from regs); issue global loads(c+1); barrier;
//   ds_read + MFMA (NO vmem in compute phase -> no vmcnt stalls).
// o-split doubles waves/CU vs round 4 (TLP hides staging + LDS latency).
// ---------------------------------------------------------------------------
__global__ __launch_bounds__(512, 6) void k1_mfma(const float* __restrict__ in,
                                                  const float* __restrict__ W1,
                                                  const int* __restrict__ maps,
                                                  double* __restrict__ I1T) {
  __shared__ double AI[KC1][66];    // [f-in-chunk][b]   C-meaned input
  __shared__ double WS[KC1][O1];    // [f-in-chunk][o]   W1 as f64
  const int tid = threadIdx.x;
  const int l   = tid & 63;
  const int w   = tid >> 6;
  const int wb  = w & 3;
  const int wo  = w >> 2;
  const int r16 = l & 15;
  const int q16 = l >> 4;
  const int b0  = (int)blockIdx.x * 64;
  const int t   = (int)blockIdx.y;

  const int4 rm = *reinterpret_cast<const int4*>(maps + l * 8);
  const int4 cm = *reinterpret_cast<const int4*>(maps + l * 8 + 4);

  // --- staging descriptors ---
  // input: 896 float4 per chunk; slot p: i = p*512+tid, row=i/14, q=i%14
  bool iact[2]; int irow[2], iq[2]; const float* ibp[2];
#pragma unroll
  for (int p = 0; p < 2; ++p) {
    const int i = p * 512 + tid;
    iact[p] = (i < 896);
    irow[p] = iact[p] ? i / 14 : 0;
    iq[p]   = i - irow[p] * 14;
    ibp[p]  = in + ((size_t)(b0 + irow[p]) * T_STEPS + t) * (FIN * 2) + iq[p] * 4;
  }
  // W1: 1400 float2 per chunk; slot p: i = p*512+tid, k=i/50, oh=2*(i%50)
  bool wact[3]; int wk[3], woh[3]; const float2* wbp[3];
#pragma unroll
  for (int p = 0; p < 3; ++p) {
    const int i = p * 512 + tid;
    wact[p] = (i < 1400);
    wk[p]   = wact[p] ? i / 50 : 0;
    woh[p]  = (i - wk[p] * 50) * 2;
    wbp[p]  = reinterpret_cast<const float2*>(W1) + ((size_t)wk[p] * O1 + woh[p]) / 2;
  }

  float4 ist[2];
  float2 wst[3];

  // prologue: issue chunk 0 loads
#pragma unroll
  for (int p = 0; p < 2; ++p) if (iact[p]) ist[p] = *reinterpret_cast<const float4*>(ibp[p]);
#pragma unroll
  for (int p = 0; p < 3; ++p) if (wact[p]) wst[p] = wbp[p][0];

  f64x4 acc[4];
#pragma unroll
  for (int n = 0; n < 4; ++n) acc[n] = (f64x4){0.0, 0.0, 0.0, 0.0};

  for (int c = 0; c < NC1; ++c) {
    __syncthreads();   // previous chunk's compute done before LDS rewrite
    // ds_write chunk c from regs
#pragma unroll
    for (int p = 0; p < 2; ++p)
      if (iact[p]) {
        AI[iq[p] * 2 + 0][irow[p]] = 0.5 * ((double)ist[p].x + (double)ist[p].y);
        AI[iq[p] * 2 + 1][irow[p]] = 0.5 * ((double)ist[p].z + (double)ist[p].w);
      }
#pragma unroll
    for (int p = 0; p < 3; ++p)
      if (wact[p]) {
        double2 wv; wv.x = (double)wst[p].x; wv.y = (double)wst[p].y;
        *reinterpret_cast<double2*>(&WS[wk[p]][woh[p]]) = wv;
      }
    // issue chunk c+1 loads (fire-and-forget; land during compute phase)
    if (c + 1 < NC1) {
#pragma unroll
      for (int p = 0; p < 2; ++p)
        if (iact[p]) ist[p] = *reinterpret_cast<const float4*>(ibp[p] + (c + 1) * 56);
#pragma unroll
      for (int p = 0; p < 3; ++p)
        if (wact[p]) wst[p] = wbp[p][(size_t)(c + 1) * (KC1 * O1 / 2)];
    }
    __syncthreads();   // chunk c visible in LDS
    // compute chunk c: pure LDS + MFMA (lgkm only)
    if (wo == 0) {
#pragma unroll
      for (int q = 0; q < KC1 / 4; ++q) {
        const double bv = AI[q * 4 + q16][wb * 16 + r16];
        const double* wr = &WS[q * 4 + q16][r16];
        acc[0] = __builtin_amdgcn_mfma_f64_16x16x4f64(wr[0],  bv, acc[0], 0, 0, 0);
        acc[1] = __builtin_amdgcn_mfma_f64_16x16x4f64(wr[16], bv, acc[1], 0, 0, 0);
        acc[2] = __builtin_amdgcn_mfma_f64_16x16x4f64(wr[32], bv, acc[2], 0, 0, 0);
        acc[3] = __builtin_amdgcn_mfma_f64_16x16x4f64(wr[48], bv, acc[3], 0, 0, 0);
      }
    } else {
#pragma unroll
      for (int q = 0; q < KC1 / 4; ++q) {
        const double bv = AI[q * 4 + q16][wb * 16 + r16];
        const double* wr = &WS[q * 4 + q16][r16];
        acc[0] = __builtin_amdgcn_mfma_f64_16x16x4f64(wr[64], bv, acc[0], 0, 0, 0);
        acc[1] = __builtin_amdgcn_mfma_f64_16x16x4f64(wr[80], bv, acc[1], 0, 0, 0);
        acc[2] = __builtin_amdgcn_mfma_f64_16x16x4f64(wr[84], bv, acc[2], 0, 0, 0);
      }
    }
  }

  double* base = I1T + (size_t)t * O1 * BATCH + (b0 + wb * 16);
  const int nt = wo ? 3 : 4;
  const int otab[2][4] = {{0, 16, 32, 48}, {64, 80, 84, 84}};
  for (int n = 0; n < nt; ++n) {
    const int o0 = otab[wo][n];
    base[(size_t)(o0 + rm.x) * BATCH + cm.x] = acc[n][0];
    base[(size_t)(o0 + rm.y) * BATCH + cm.y] = acc[n][1];
    base[(size_t)(o0 + rm.z) * BATCH + cm.z] = acc[n][2];
    base[(size_t)(o0 + rm.w) * BATCH + cm.w] = acc[n][3];
  }
}

// ---------------------------------------------------------------------------
// K2: BN stats per (t,o) row: mu, rstd. One wave per row.
// ---------------------------------------------------------------------------
__global__ __launch_bounds__(256) void k2_bnstats(const double* __restrict__ I1T,
                                                  double* __restrict__ mu,
                                                  double* __restrict__ rstd) {
  const int r    = blockIdx.x * 4 + (threadIdx.x >> 6);
  const int lane = threadIdx.x & 63;
  const double2* row2 = reinterpret_cast<const double2*>(I1T + (size_t)r * BATCH) + lane * 4;
  double v[8];
#pragma unroll
  for (int u = 0; u < 4; ++u) {
    double2 p = row2[u];
    v[2 * u] = p.x; v[2 * u + 1] = p.y;
  }
  double s = 0.0;
#pragma unroll
  for (int u = 0; u < 8; ++u) s += v[u];
#pragma unroll
  for (int m = 32; m >= 1; m >>= 1) s += __shfl_xor(s, m, 64);
  const double mean = s / 512.0;
  double q = 0.0;
#pragma unroll
  for (int u = 0; u < 8; ++u) { double d = v[u] - mean; q += d * d; }
#pragma unroll
  for (int m = 32; m >= 1; m >>= 1) q += __shfl_xor(q, m, 64);
  if (lane == 0) {
    mu[r]   = mean;
    rstd[r] = 1.0 / sqrt(q / 512.0 + 1e-5);
  }
}

// ---------------------------------------------------------------------------
// K3: layer-1 LIF scan. Block = o, thread = b.
// ---------------------------------------------------------------------------
__global__ __launch_bounds__(512) void k3_lif1(const double* __restrict__ I1T,
                                               const double* __restrict__ mu,
                                               const double* __restrict__ rstd,
                                               const float* __restrict__ scale,
                                               const float* __restrict__ bias,
                                               float* __restrict__ z1T) {
  const int o = blockIdx.x;
  const int b = threadIdx.x;
  const double sc = (double)scale[o], bs = (double)bias[o];
  double v = 0.0;
  for (int tc = 0; tc < T_STEPS; tc += 10) {
    double x[10], muv[10], rsv[10];
#pragma unroll
    for (int u = 0; u < 10; ++u) {
      const int t = tc + u;
      x[u]   = I1T[((size_t)t * O1 + o) * BATCH + b];
      muv[u] = mu[t * O1 + o];
      rsv[u] = rstd[t * O1 + o];
    }
#pragma unroll
    for (int u = 0; u < 10; ++u) {
      const double i = ((x[u] - muv[u]) * rsv[u]) * sc + bs;
      v = 0.95 * v + i;
      const bool z = (v > 1.0);
      z1T[((size_t)(tc + u) * O1 + o) * BATCH + b] = z ? 1.0f : 0.0f;
      if (z) v = 0.0;
    }
  }
}

// ---------------------------------------------------------------------------
// K4: I2[t][j][b] = sum_o z1T[t][o][b] * W2[o][j].
// ---------------------------------------------------------------------------
__global__ __launch_bounds__(512) void k4_proj2(const float* __restrict__ z1T,
                                                const float* __restrict__ W2,
                                                double* __restrict__ I2) {
  __shared__ double W2_lds[O1 * O2];
  const int t = blockIdx.x;
  const int b = threadIdx.x;
  for (int i = threadIdx.x; i < O1 * O2; i += 512) W2_lds[i] = (double)W2[i];
  __syncthreads();
  double acc[O2];
#pragma unroll
  for (int j = 0; j < O2; ++j) acc[j] = 0.0;
  for (int o = 0; o < O1; ++o) {
    const double z = (double)z1T[((size_t)t * O1 + o) * BATCH + b];
#pragma unroll
    for (int j = 0; j < O2; ++j) acc[j] += z * W2_lds[o * O2 + j];
  }
#pragma unroll
  for (int j = 0; j < O2; ++j)
    I2[((size_t)t * O2 + j) * BATCH + b] = acc[j];
}

// ---------------------------------------------------------------------------
// K5: layer-2 LIF scan + time-mean.
// ---------------------------------------------------------------------------
__global__ __launch_bounds__(512) void k5_lif2(const double* __restrict__ I2,
                                               float* __restrict__ out) {
  const int j = blockIdx.x;
  const int b = threadIdx.x;
  double v = 0.0;
  int cnt = 0;
  for (int tc = 0; tc < T_STEPS; tc += 10) {
    double x[10];
#pragma unroll
    for (int u = 0; u < 10; ++u)
      x[u] = I2[((size_t)(tc + u) * O2 + j) * BATCH + b];
#pragma unroll
    for (int u = 0; u < 10; ++u) {
      v = 0.95 * v + x[u];
      if (v > 1.0) { ++cnt; v = 0.0; }
    }
  }
  out[b * O2 + j] = (float)((double)cnt / 100.0);
}

// ---------------------------------------------------------------------------
extern "C" void kernel_launch(void* const* d_in, const int* in_sizes, int n_in,
                              void* d_out, int out_size, void* d_ws, size_t ws_size,
                              hipStream_t stream) {
  const float* in    = (const float*)d_in[0];
  const float* W1    = (const float*)d_in[2];
  const float* scale = (const float*)d_in[3];
  const float* bias  = (const float*)d_in[4];
  const float* W2    = (const float*)d_in[5];
  float* out = (float*)d_out;

  char* ws = (char*)d_ws;
  size_t off = 0;
  int*    maps = (int*)(ws + off);    off += 4096;
  double* I1T  = (double*)(ws + off); off += (size_t)T_STEPS * O1 * BATCH * sizeof(double);
  double* mu   = (double*)(ws + off); off += (size_t)T_STEPS * O1 * sizeof(double);
  double* rstd = (double*)(ws + off); off += (size_t)T_STEPS * O1 * sizeof(double);
  float*  z1T  = (float*)(ws + off);  off += (size_t)T_STEPS * O1 * BATCH * sizeof(float);
  double* I2   = (double*)(ws + off); off += (size_t)T_STEPS * O2 * BATCH * sizeof(double);

  k0_probe  <<<dim3(1), 64, 0, stream>>>(maps);
  k1_mfma   <<<dim3(BATCH / 64, T_STEPS), 512, 0, stream>>>(in, W1, maps, I1T);
  k2_bnstats<<<dim3(T_STEPS * O1 / 4), 256, 0, stream>>>(I1T, mu, rstd);
  k3_lif1   <<<dim3(O1), 512, 0, stream>>>(I1T, mu, rstd, scale, bias, z1T);
  k4_proj2  <<<dim3(T_STEPS), 512, 0, stream>>>(z1T, W2, I2);
  k5_lif2   <<<dim3(O2), 512, 0, stream>>>(I2, out);
}

// Round 7
// 256.782 us; speedup vs baseline: 2.7577x; 1.6792x over previous
//
#include <hip/hip_runtime.h>

#define T_STEPS 100
#define BATCH   512
#define FIN     784
#define O1      100
#define O2      10
#define KC1     28      // K-chunk (784 = 28 * 28)
#define NC1     (FIN / KC1)

typedef __attribute__((ext_vector_type(4))) double f64x4;

// ---------------------------------------------------------------------------
// K0: f64-MFMA D-layout probe (validated rounds 3-6). Assumes only A-row =
// lane&15, B-col = lane&15. maps[l*8+r] = D-row, maps[l*8+4+r] = D-col.
// ---------------------------------------------------------------------------
__global__ __launch_bounds__(64) void k0_probe(int* __restrict__ maps) {
  const int l = threadIdx.x;
  const f64x4 z = {0.0, 0.0, 0.0, 0.0};
  f64x4 pr = __builtin_amdgcn_mfma_f64_16x16x4f64((double)(l & 15), 0.25, z, 0, 0, 0);
  f64x4 pc = __builtin_amdgcn_mfma_f64_16x16x4f64(0.25, (double)(l & 15), z, 0, 0, 0);
#pragma unroll
  for (int r = 0; r < 4; ++r) {
    int rm = (int)(pr[r] + 0.5); rm = rm < 0 ? 0 : (rm > 15 ? 15 : rm);
    int cm = (int)(pc[r] + 0.5); cm = cm < 0 ? 0 : (cm > 15 ? 15 : cm);
    maps[l * 8 + r]     = rm;
    maps[l * 8 + 4 + r] = cm;
  }
}

// ---------------------------------------------------------------------------
// K1 v5: fused C-mean + f64 MFMA GEMM.  Same structure as v4 (8-wave o-split,
// reg-staged prefetch, vmem-free compute phase) with ONE fix: the epilogue
// store loop is now fully static per wo-branch. v4's runtime-bounded
// `for(n<nt) acc[n]` demoted acc to scratch (rule #20): VGPR_Count=40,
// WRITE_SIZE 1.24 GB of spill traffic. Static stores keep acc in VGPRs.
// ---------------------------------------------------------------------------
__global__ __launch_bounds__(512, 6) void k1_mfma(const float* __restrict__ in,
                                                  const float* __restrict__ W1,
                                                  const int* __restrict__ maps,
                                                  double* __restrict__ I1T) {
  __shared__ double AI[KC1][66];    // [f-in-chunk][b]   C-meaned input
  __shared__ double WS[KC1][O1];    // [f-in-chunk][o]   W1 as f64
  const int tid = threadIdx.x;
  const int l   = tid & 63;
  const int w   = tid >> 6;
  const int wb  = w & 3;
  const int wo  = w >> 2;
  const int r16 = l & 15;
  const int q16 = l >> 4;
  const int b0  = (int)blockIdx.x * 64;
  const int t   = (int)blockIdx.y;

  const int4 rm = *reinterpret_cast<const int4*>(maps + l * 8);
  const int4 cm = *reinterpret_cast<const int4*>(maps + l * 8 + 4);

  // --- staging descriptors ---
  // input: 896 float4 per chunk; slot p: i = p*512+tid, row=i/14, q=i%14
  bool iact[2]; int irow[2], iq[2]; const float* ibp[2];
#pragma unroll
  for (int p = 0; p < 2; ++p) {
    const int i = p * 512 + tid;
    iact[p] = (i < 896);
    irow[p] = iact[p] ? i / 14 : 0;
    iq[p]   = i - irow[p] * 14;
    ibp[p]  = in + ((size_t)(b0 + irow[p]) * T_STEPS + t) * (FIN * 2) + iq[p] * 4;
  }
  // W1: 1400 float2 per chunk; slot p: i = p*512+tid, k=i/50, oh=2*(i%50)
  bool wact[3]; int wk[3], woh[3]; const float2* wbp[3];
#pragma unroll
  for (int p = 0; p < 3; ++p) {
    const int i = p * 512 + tid;
    wact[p] = (i < 1400);
    wk[p]   = wact[p] ? i / 50 : 0;
    woh[p]  = (i - wk[p] * 50) * 2;
    wbp[p]  = reinterpret_cast<const float2*>(W1) + ((size_t)wk[p] * O1 + woh[p]) / 2;
  }

  float4 ist[2];
  float2 wst[3];

  // prologue: issue chunk 0 loads
#pragma unroll
  for (int p = 0; p < 2; ++p) if (iact[p]) ist[p] = *reinterpret_cast<const float4*>(ibp[p]);
#pragma unroll
  for (int p = 0; p < 3; ++p) if (wact[p]) wst[p] = wbp[p][0];

  f64x4 acc0 = {0.0, 0.0, 0.0, 0.0};
  f64x4 acc1 = {0.0, 0.0, 0.0, 0.0};
  f64x4 acc2 = {0.0, 0.0, 0.0, 0.0};
  f64x4 acc3 = {0.0, 0.0, 0.0, 0.0};

  for (int c = 0; c < NC1; ++c) {
    __syncthreads();   // previous chunk's compute done before LDS rewrite
    // ds_write chunk c from regs
#pragma unroll
    for (int p = 0; p < 2; ++p)
      if (iact[p]) {
        AI[iq[p] * 2 + 0][irow[p]] = 0.5 * ((double)ist[p].x + (double)ist[p].y);
        AI[iq[p] * 2 + 1][irow[p]] = 0.5 * ((double)ist[p].z + (double)ist[p].w);
      }
#pragma unroll
    for (int p = 0; p < 3; ++p)
      if (wact[p]) {
        double2 wv; wv.x = (double)wst[p].x; wv.y = (double)wst[p].y;
        *reinterpret_cast<double2*>(&WS[wk[p]][woh[p]]) = wv;
      }
    // issue chunk c+1 loads (fire-and-forget; land during compute phase)
    if (c + 1 < NC1) {
#pragma unroll
      for (int p = 0; p < 2; ++p)
        if (iact[p]) ist[p] = *reinterpret_cast<const float4*>(ibp[p] + (c + 1) * 56);
#pragma unroll
      for (int p = 0; p < 3; ++p)
        if (wact[p]) wst[p] = wbp[p][(size_t)(c + 1) * (KC1 * O1 / 2)];
    }
    __syncthreads();   // chunk c visible in LDS
    // compute chunk c: pure LDS + MFMA (lgkm only)
    if (wo == 0) {
#pragma unroll
      for (int q = 0; q < KC1 / 4; ++q) {
        const double bv = AI[q * 4 + q16][wb * 16 + r16];
        const double* wr = &WS[q * 4 + q16][r16];
        acc0 = __builtin_amdgcn_mfma_f64_16x16x4f64(wr[0],  bv, acc0, 0, 0, 0);
        acc1 = __builtin_amdgcn_mfma_f64_16x16x4f64(wr[16], bv, acc1, 0, 0, 0);
        acc2 = __builtin_amdgcn_mfma_f64_16x16x4f64(wr[32], bv, acc2, 0, 0, 0);
        acc3 = __builtin_amdgcn_mfma_f64_16x16x4f64(wr[48], bv, acc3, 0, 0, 0);
      }
    } else {
#pragma unroll
      for (int q = 0; q < KC1 / 4; ++q) {
        const double bv = AI[q * 4 + q16][wb * 16 + r16];
        const double* wr = &WS[q * 4 + q16][r16];
        acc0 = __builtin_amdgcn_mfma_f64_16x16x4f64(wr[64], bv, acc0, 0, 0, 0);
        acc1 = __builtin_amdgcn_mfma_f64_16x16x4f64(wr[80], bv, acc1, 0, 0, 0);
        acc2 = __builtin_amdgcn_mfma_f64_16x16x4f64(wr[84], bv, acc2, 0, 0, 0);
      }
    }
  }

  double* base = I1T + (size_t)t * O1 * BATCH + (b0 + wb * 16);
#define STORE_TILE(ACC, O0)                                          \
  {                                                                  \
    base[(size_t)((O0) + rm.x) * BATCH + cm.x] = (ACC)[0];           \
    base[(size_t)((O0) + rm.y) * BATCH + cm.y] = (ACC)[1];           \
    base[(size_t)((O0) + rm.z) * BATCH + cm.z] = (ACC)[2];           \
    base[(size_t)((O0) + rm.w) * BATCH + cm.w] = (ACC)[3];           \
  }
  if (wo == 0) {
    STORE_TILE(acc0, 0);
    STORE_TILE(acc1, 16);
    STORE_TILE(acc2, 32);
    STORE_TILE(acc3, 48);
  } else {
    STORE_TILE(acc0, 64);
    STORE_TILE(acc1, 80);
    STORE_TILE(acc2, 84);
  }
#undef STORE_TILE
}

// ---------------------------------------------------------------------------
// K2: BN stats per (t,o) row: mu, rstd. One wave per row.
// ---------------------------------------------------------------------------
__global__ __launch_bounds__(256) void k2_bnstats(const double* __restrict__ I1T,
                                                  double* __restrict__ mu,
                                                  double* __restrict__ rstd) {
  const int r    = blockIdx.x * 4 + (threadIdx.x >> 6);
  const int lane = threadIdx.x & 63;
  const double2* row2 = reinterpret_cast<const double2*>(I1T + (size_t)r * BATCH) + lane * 4;
  double v[8];
#pragma unroll
  for (int u = 0; u < 4; ++u) {
    double2 p = row2[u];
    v[2 * u] = p.x; v[2 * u + 1] = p.y;
  }
  double s = 0.0;
#pragma unroll
  for (int u = 0; u < 8; ++u) s += v[u];
#pragma unroll
  for (int m = 32; m >= 1; m >>= 1) s += __shfl_xor(s, m, 64);
  const double mean = s / 512.0;
  double q = 0.0;
#pragma unroll
  for (int u = 0; u < 8; ++u) { double d = v[u] - mean; q += d * d; }
#pragma unroll
  for (int m = 32; m >= 1; m >>= 1) q += __shfl_xor(q, m, 64);
  if (lane == 0) {
    mu[r]   = mean;
    rstd[r] = 1.0 / sqrt(q / 512.0 + 1e-5);
  }
}

// ---------------------------------------------------------------------------
// K3: layer-1 LIF scan. Block = o, thread = b.
// ---------------------------------------------------------------------------
__global__ __launch_bounds__(512) void k3_lif1(const double* __restrict__ I1T,
                                               const double* __restrict__ mu,
                                               const double* __restrict__ rstd,
                                               const float* __restrict__ scale,
                                               const float* __restrict__ bias,
                                               float* __restrict__ z1T) {
  const int o = blockIdx.x;
  const int b = threadIdx.x;
  const double sc = (double)scale[o], bs = (double)bias[o];
  double v = 0.0;
  for (int tc = 0; tc < T_STEPS; tc += 10) {
    double x[10], muv[10], rsv[10];
#pragma unroll
    for (int u = 0; u < 10; ++u) {
      const int t = tc + u;
      x[u]   = I1T[((size_t)t * O1 + o) * BATCH + b];
      muv[u] = mu[t * O1 + o];
      rsv[u] = rstd[t * O1 + o];
    }
#pragma unroll
    for (int u = 0; u < 10; ++u) {
      const double i = ((x[u] - muv[u]) * rsv[u]) * sc + bs;
      v = 0.95 * v + i;
      const bool z = (v > 1.0);
      z1T[((size_t)(tc + u) * O1 + o) * BATCH + b] = z ? 1.0f : 0.0f;
      if (z) v = 0.0;
    }
  }
}

// ---------------------------------------------------------------------------
// K4: I2[t][j][b] = sum_o z1T[t][o][b] * W2[o][j].
// ---------------------------------------------------------------------------
__global__ __launch_bounds__(512) void k4_proj2(const float* __restrict__ z1T,
                                                const float* __restrict__ W2,
                                                double* __restrict__ I2) {
  __shared__ double W2_lds[O1 * O2];
  const int t = blockIdx.x;
  const int b = threadIdx.x;
  for (int i = threadIdx.x; i < O1 * O2; i += 512) W2_lds[i] = (double)W2[i];
  __syncthreads();
  double acc[O2];
#pragma unroll
  for (int j = 0; j < O2; ++j) acc[j] = 0.0;
  for (int o = 0; o < O1; ++o) {
    const double z = (double)z1T[((size_t)t * O1 + o) * BATCH + b];
#pragma unroll
    for (int j = 0; j < O2; ++j) acc[j] += z * W2_lds[o * O2 + j];
  }
#pragma unroll
  for (int j = 0; j < O2; ++j)
    I2[((size_t)t * O2 + j) * BATCH + b] = acc[j];
}

// ---------------------------------------------------------------------------
// K5: layer-2 LIF scan + time-mean.
// ---------------------------------------------------------------------------
__global__ __launch_bounds__(512) void k5_lif2(const double* __restrict__ I2,
                                               float* __restrict__ out) {
  const int j = blockIdx.x;
  const int b = threadIdx.x;
  double v = 0.0;
  int cnt = 0;
  for (int tc = 0; tc < T_STEPS; tc += 10) {
    double x[10];
#pragma unroll
    for (int u = 0; u < 10; ++u)
      x[u] = I2[((size_t)(tc + u) * O2 + j) * BATCH + b];
#pragma unroll
    for (int u = 0; u < 10; ++u) {
      v = 0.95 * v + x[u];
      if (v > 1.0) { ++cnt; v = 0.0; }
    }
  }
  out[b * O2 + j] = (float)((double)cnt / 100.0);
}

// ---------------------------------------------------------------------------
extern "C" void kernel_launch(void* const* d_in, const int* in_sizes, int n_in,
                              void* d_out, int out_size, void* d_ws, size_t ws_size,
                              hipStream_t stream) {
  const float* in    = (const float*)d_in[0];
  const float* W1    = (const float*)d_in[2];
  const float* scale = (const float*)d_in[3];
  const float* bias  = (const float*)d_in[4];
  const float* W2    = (const float*)d_in[5];
  float* out = (float*)d_out;

  char* ws = (char*)d_ws;
  size_t off = 0;
  int*    maps = (int*)(ws + off);    off += 4096;
  double* I1T  = (double*)(ws + off); off += (size_t)T_STEPS * O1 * BATCH * sizeof(double);
  double* mu   = (double*)(ws + off); off += (size_t)T_STEPS * O1 * sizeof(double);
  double* rstd = (double*)(ws + off); off += (size_t)T_STEPS * O1 * sizeof(double);
  float*  z1T  = (float*)(ws + off);  off += (size_t)T_STEPS * O1 * BATCH * sizeof(float);
  double* I2   = (double*)(ws + off); off += (size_t)T_STEPS * O2 * BATCH * sizeof(double);

  k0_probe  <<<dim3(1), 64, 0, stream>>>(maps);
  k1_mfma   <<<dim3(BATCH / 64, T_STEPS), 512, 0, stream>>>(in, W1, maps, I1T);
  k2_bnstats<<<dim3(T_STEPS * O1 / 4), 256, 0, stream>>>(I1T, mu, rstd);
  k3_lif1   <<<dim3(O1), 512, 0, stream>>>(I1T, mu, rstd, scale, bias, z1T);
  k4_proj2  <<<dim3(T_STEPS), 512, 0, stream>>>(z1T, W2, I2);
  k5_lif2   <<<dim3(O2), 512, 0, stream>>>(I2, out);
}